// Round 14
// baseline (37.973 us; speedup 1.0000x reference)
//
#include <hip/hip_runtime.h>
#include <math.h>

// FrequencyAdaptiveNorm: multi-scale (w=5,10,20) centered sliding-window
// normalization over L, softmax-weighted fusion.
// x: (B=32, L=2048, F=256) f32, weights: (3,) f32, out: same shape.
//
// v14 = v9 structure (ring[24], prefetch distance 4, launch_bounds(256,8),
// algebraic norm from v13) with ONE change: TL 32 -> 16.
// Rationale: v13 books show ~14us of non-overlap with occupancy ~45% --
// the grid supplied exactly ONE wave generation (8192 waves for 8192
// slots), so ramp+drain cap average residency. TL=16 doubles the grid to
// 16384 waves (2 generations): retiring blocks are backfilled, sustaining
// residency. Cost: +10% VALU (init amortization), FETCH 52->~70MB (halo),
// bought against a hoped ~1.5x issue-throughput gain.

#define B_ 32
#define L_ 2048
#define F_ 256
#define TL 16     // L-chunk per block; grid = (128, 32) = 4096 blocks
#define NR 24     // ring size; ring[d] = x[j-10+d]; insert at d=23 (j+14)

#define RSQ(x) __builtin_amdgcn_rsqf(x)   // single v_rsq_f32, ~1 ulp

__device__ __forceinline__ float fin(float v) {
    return isfinite(v) ? v : 0.0f;   // nan_to_num(nan=0, +inf=0, -inf=0)
}

// one scale's contribution: W = window width, C = W*W*eps
__device__ __forceinline__ float scale_term(const float xc, const float s,
                                            const float q, const float W,
                                            const float C) {
    float P = fmaf(-s, s, C);          // C - s^2
    P = fmaf(q, W, P);                 // q*W - s^2 + W^2*eps
    P = fmaxf(P, C);                   // W^2*(max(var,0)+eps)
    const float n = fmaf(W, xc, -s);   // W*(xc - mean)
    return n * RSQ(P);                 // (xc-mean)*rsqrt(var+eps)
}

template <bool CHECKED>
__device__ __forceinline__ void run_chunk(const float* __restrict__ xb,
                                          float* __restrict__ ob,
                                          const int l0,
                                          const float ws5, const float ws10,
                                          const float ws20) {
    const float C5  = 25.0f  * 1e-5f;
    const float C10 = 100.0f * 1e-5f;
    const float C20 = 400.0f * 1e-5f;

    // delay line: ring[d] = x[l0-10+d], d = 0..NR-1
    float ring[NR];
#pragma unroll
    for (int d = 0; d < NR; ++d) {
        const int l = l0 - 10 + d;
        float v;
        if (CHECKED)
            v = ((unsigned)l < (unsigned)L_) ? xb[l * F_] : 0.0f;
        else
            v = xb[l * F_];
        ring[d] = fin(v);
    }

    // running sums at j=l0: w5=ring[8..12], w10=ring[5..14], w20=ring[0..19]
    float s5 = 0.f, q5 = 0.f, s10 = 0.f, q10 = 0.f, s20 = 0.f, q20 = 0.f;
#pragma unroll
    for (int d = 0; d < 20; ++d) { s20 += ring[d]; q20 = fmaf(ring[d], ring[d], q20); }
#pragma unroll
    for (int d = 5; d < 15; ++d) { s10 += ring[d]; q10 = fmaf(ring[d], ring[d], q10); }
#pragma unroll
    for (int d = 8; d < 13; ++d) { s5  += ring[d]; q5  = fmaf(ring[d], ring[d], q5);  }

#pragma unroll
    for (int t = 0; t < TL; ++t) {
        const int j = l0 + t;

        // ring-insert load, consumed 3-4 iterations later
        float vnew;
        if (CHECKED) {
            const int ln = j + 14;
            vnew = ((unsigned)ln < (unsigned)L_) ? fin(xb[ln * F_]) : 0.0f;
        } else {
            vnew = fin(xb[(j + 14) * F_]);
        }

        const float xc = ring[10];
        float acc = 0.0f;

        if (!CHECKED || (j >= 2 && j <= L_ - 3))            // w=5
            acc = fmaf(ws5,  scale_term(xc, s5,  q5,  5.0f,  C5),  acc);
        if (!CHECKED || (j >= 5 && j <= L_ - 5))            // w=10
            acc = fmaf(ws10, scale_term(xc, s10, q10, 10.0f, C10), acc);
        if (!CHECKED || (j >= 10 && j <= L_ - 10))          // w=20
            acc = fmaf(ws20, scale_term(xc, s20, q20, 20.0f, C20), acc);

        __builtin_nontemporal_store(acc, &ob[j * F_]);

        // slide windows j -> j+1:  s += a-r;  q += (a-r)(a+r)
        {
            const float a = ring[13], r = ring[8];
            const float d = a - r, p = a + r;
            s5 += d; q5 = fmaf(d, p, q5);
        }
        {
            const float a = ring[15], r = ring[5];
            const float d = a - r, p = a + r;
            s10 += d; q10 = fmaf(d, p, q10);
        }
        {
            const float a = ring[20], r = ring[0];
            const float d = a - r, p = a + r;
            s20 += d; q20 = fmaf(d, p, q20);
        }

        // shift delay line (compiler renames; v12 proved zero real movs)
#pragma unroll
        for (int d = 0; d < NR - 1; ++d) ring[d] = ring[d + 1];
        ring[NR - 1] = vnew;
    }
}

__global__ __launch_bounds__(256, 8)
void fan_kernel(const float* __restrict__ x,
                const float* __restrict__ w,
                float* __restrict__ out) {
    const int f  = threadIdx.x;           // 0..255 == F
    const int b  = blockIdx.y;
    const int l0 = blockIdx.x * TL;
    const float* xb = x   + (size_t)b * L_ * F_ + f;
    float*       ob = out + (size_t)b * L_ * F_ + f;

    // softmax over the 3 fusion logits (uniform across threads)
    const float w0 = w[0], w1 = w[1], w2 = w[2];
    const float m  = fmaxf(w0, fmaxf(w1, w2));
    const float e0 = expf(w0 - m), e1 = expf(w1 - m), e2 = expf(w2 - m);
    const float inv = 1.0f / (e0 + e1 + e2);
    const float ws5 = e0 * inv, ws10 = e1 * inv, ws20 = e2 * inv;

    // interior blocks 1..126: loads span [l0-10, l0+TL+13] -> in range
    // (l0>=16 -> l0-10>=6; l0<=2016 -> l0+29<=2045), and all three window
    // validity ranges cover every j (l0>=16>=10; l0+15<=2031<=2038).
    if (blockIdx.x != 0 && blockIdx.x != gridDim.x - 1)
        run_chunk<false>(xb, ob, l0, ws5, ws10, ws20);
    else
        run_chunk<true>(xb, ob, l0, ws5, ws10, ws20);
}

extern "C" void kernel_launch(void* const* d_in, const int* in_sizes, int n_in,
                              void* d_out, int out_size, void* d_ws, size_t ws_size,
                              hipStream_t stream) {
    const float* x = (const float*)d_in[0];
    const float* w = (const float*)d_in[1];
    float* out = (float*)d_out;
    (void)in_sizes; (void)n_in; (void)out_size; (void)d_ws; (void)ws_size;

    dim3 grid(L_ / TL, B_);   // (128, 32) = 4096 blocks
    dim3 block(F_);           // 256 threads, one per feature column
    hipLaunchKernelGGL(fan_kernel, grid, block, 0, stream, x, w, out);
}

// Round 16
// 33.772 us; speedup vs baseline: 1.1244x; 1.1244x over previous
//
#include <hip/hip_runtime.h>
#include <math.h>

// FrequencyAdaptiveNorm: multi-scale (w=5,10,20) centered sliding-window
// normalization over L, softmax-weighted fusion.
// x: (B=32, L=2048, F=256) f32, weights: (3,) f32, out: same shape.
//
// v15b: float2-over-f (2 columns/thread), fixed compile: use clang
// ext_vector f32x2 (native vector) for loads + nontemporal store --
// __builtin_nontemporal_store rejects HIP_vector_type<float,2>.
// One dwordx2 load + one dwordx2 store per 2 elements; addressing/loop
// amortized 2x; two independent dep chains (ILP). No [c]-indexed arrays,
// no address-taken locals (v3 scratch lesson): two separate static-index
// rings rX/rY + all-scalar sums. TL=16, block(128,2), grid(64,32) = 8192
// waves. launch_bounds(256,4): 128-VGPR cap for the ~80-VGPR live set.
// Tripwire: WRITE_SIZE must stay exactly 65536 KB.

#define B_ 32
#define L_ 2048
#define F_ 256
#define TL 16     // rows per chunk; block covers 2 chunks; grid = (64, 32)
#define NR 24     // ring: r[d] = x[j-10+d]; insert at d=23 (x[j+14])

typedef float f32x2 __attribute__((ext_vector_type(2)));

#define RSQ(x) __builtin_amdgcn_rsqf(x)   // single v_rsq_f32, ~1 ulp

__device__ __forceinline__ float fin(float v) {
    return isfinite(v) ? v : 0.0f;   // nan_to_num(nan=0, +inf=0, -inf=0)
}

// one scale's contribution: W = window width, C = W*W*eps
__device__ __forceinline__ float scale_term(const float xc, const float s,
                                            const float q, const float W,
                                            const float C) {
    float P = fmaf(-s, s, C);          // C - s^2
    P = fmaf(q, W, P);                 // q*W - s^2 + W^2*eps
    P = fmaxf(P, C);                   // W^2*(max(var,0)+eps)
    return fmaf(W, xc, -s) * RSQ(P);   // (xc-mean)*rsqrt(var+eps)
}

template <bool CHECKED>
__device__ __forceinline__ void run_chunk2(const float* __restrict__ xb,
                                           float* __restrict__ ob,
                                           const int l0,
                                           const float ws5, const float ws10,
                                           const float ws20) {
    const float C5  = 25.0f  * 1e-5f;
    const float C10 = 100.0f * 1e-5f;
    const float C20 = 400.0f * 1e-5f;

    // two independent delay lines (adjacent f columns), static indices only
    float rX[NR], rY[NR];
#pragma unroll
    for (int d = 0; d < NR; ++d) {
        const int l = l0 - 10 + d;
        f32x2 v = (f32x2)(0.f);
        if (!CHECKED || (unsigned)l < (unsigned)L_)
            v = *reinterpret_cast<const f32x2*>(xb + (size_t)l * F_);
        rX[d] = fin(v.x);
        rY[d] = fin(v.y);
    }

    // running sums at j=l0 (all scalars; X and Y fully independent)
    float s5X = 0.f, q5X = 0.f, s10X = 0.f, q10X = 0.f, s20X = 0.f, q20X = 0.f;
    float s5Y = 0.f, q5Y = 0.f, s10Y = 0.f, q10Y = 0.f, s20Y = 0.f, q20Y = 0.f;
#pragma unroll
    for (int d = 0; d < 20; ++d) {
        s20X += rX[d]; q20X = fmaf(rX[d], rX[d], q20X);
        s20Y += rY[d]; q20Y = fmaf(rY[d], rY[d], q20Y);
    }
#pragma unroll
    for (int d = 5; d < 15; ++d) {
        s10X += rX[d]; q10X = fmaf(rX[d], rX[d], q10X);
        s10Y += rY[d]; q10Y = fmaf(rY[d], rY[d], q10Y);
    }
#pragma unroll
    for (int d = 8; d < 13; ++d) {
        s5X += rX[d]; q5X = fmaf(rX[d], rX[d], q5X);
        s5Y += rY[d]; q5Y = fmaf(rY[d], rY[d], q5Y);
    }

#pragma unroll
    for (int t = 0; t < TL; ++t) {
        const int j = l0 + t;

        // ring-insert load (one dwordx2 for both columns), used 4 iters later
        f32x2 vn = (f32x2)(0.f);
        if (!CHECKED || (unsigned)(j + 14) < (unsigned)L_)
            vn = *reinterpret_cast<const f32x2*>(xb + (size_t)(j + 14) * F_);
        const float vnX = fin(vn.x), vnY = fin(vn.y);

        float accX = 0.f, accY = 0.f;
        if (!CHECKED || (j >= 2 && j <= L_ - 3)) {          // w=5
            accX = fmaf(ws5, scale_term(rX[10], s5X, q5X, 5.0f, C5), accX);
            accY = fmaf(ws5, scale_term(rY[10], s5Y, q5Y, 5.0f, C5), accY);
        }
        if (!CHECKED || (j >= 5 && j <= L_ - 5)) {          // w=10
            accX = fmaf(ws10, scale_term(rX[10], s10X, q10X, 10.0f, C10), accX);
            accY = fmaf(ws10, scale_term(rY[10], s10Y, q10Y, 10.0f, C10), accY);
        }
        if (!CHECKED || (j >= 10 && j <= L_ - 10)) {        // w=20
            accX = fmaf(ws20, scale_term(rX[10], s20X, q20X, 20.0f, C20), accX);
            accY = fmaf(ws20, scale_term(rY[10], s20Y, q20Y, 20.0f, C20), accY);
        }
        f32x2 o; o.x = accX; o.y = accY;
        __builtin_nontemporal_store(o, reinterpret_cast<f32x2*>(ob + (size_t)j * F_));

        // slide windows j -> j+1 (two independent chains)
        { const float a = rX[13], r = rX[8],  d = a - r, p = a + r; s5X  += d; q5X  = fmaf(d, p, q5X);  }
        { const float a = rY[13], r = rY[8],  d = a - r, p = a + r; s5Y  += d; q5Y  = fmaf(d, p, q5Y);  }
        { const float a = rX[15], r = rX[5],  d = a - r, p = a + r; s10X += d; q10X = fmaf(d, p, q10X); }
        { const float a = rY[15], r = rY[5],  d = a - r, p = a + r; s10Y += d; q10Y = fmaf(d, p, q10Y); }
        { const float a = rX[20], r = rX[0],  d = a - r, p = a + r; s20X += d; q20X = fmaf(d, p, q20X); }
        { const float a = rY[20], r = rY[0],  d = a - r, p = a + r; s20Y += d; q20Y = fmaf(d, p, q20Y); }

        // shift both delay lines (compiler renames; v12 proved zero movs)
#pragma unroll
        for (int d = 0; d < NR - 1; ++d) { rX[d] = rX[d + 1]; rY[d] = rY[d + 1]; }
        rX[NR - 1] = vnX;
        rY[NR - 1] = vnY;
    }
}

__global__ __launch_bounds__(256, 4)
void fan_kernel(const float* __restrict__ x,
                const float* __restrict__ w,
                float* __restrict__ out) {
    const int f0 = threadIdx.x * 2;                       // 0,2,..,254
    const int b  = blockIdx.y;
    const int l0 = (blockIdx.x * 2 + threadIdx.y) * TL;   // chunk of 16 rows
    const float* xb = x   + (size_t)b * L_ * F_ + f0;
    float*       ob = out + (size_t)b * L_ * F_ + f0;

    // softmax over the 3 fusion logits (uniform across threads)
    const float w0 = w[0], w1 = w[1], w2 = w[2];
    const float m  = fmaxf(w0, fmaxf(w1, w2));
    const float e0 = expf(w0 - m), e1 = expf(w1 - m), e2 = expf(w2 - m);
    const float inv = 1.0f / (e0 + e1 + e2);
    const float ws5 = e0 * inv, ws10 = e1 * inv, ws20 = e2 * inv;

    // interior blocks 1..62: chunks l0 in [32, 2000] -> loads span
    // [l0-10, l0+29] in range; all window validity ranges cover every j.
    // Edge blocks 0 and 63 contain the true edge chunks (0 and 2032).
    if (blockIdx.x != 0 && blockIdx.x != gridDim.x - 1)
        run_chunk2<false>(xb, ob, l0, ws5, ws10, ws20);
    else
        run_chunk2<true>(xb, ob, l0, ws5, ws10, ws20);
}

extern "C" void kernel_launch(void* const* d_in, const int* in_sizes, int n_in,
                              void* d_out, int out_size, void* d_ws, size_t ws_size,
                              hipStream_t stream) {
    const float* x = (const float*)d_in[0];
    const float* w = (const float*)d_in[1];
    float* out = (float*)d_out;
    (void)in_sizes; (void)n_in; (void)out_size; (void)d_ws; (void)ws_size;

    dim3 grid(L_ / (TL * 2), B_);   // (64, 32) = 2048 blocks
    dim3 block(F_ / 2, 2);          // 128 f-pairs x 2 L-chunks = 256 threads
    hipLaunchKernelGGL(fan_kernel, grid, block, 0, stream, x, w, out);
}